// Round 10
// baseline (1507.096 us; speedup 1.0000x reference)
//
#include <hip/hip_runtime.h>
#include <hip/hip_bf16.h>
#include <math.h>

// Problem constants (fixed by setup_inputs). All inputs/output are fp32
// (established round 5). Internal compute: bf16 MFMA + fp32 accumulation.
#define NN     65536
#define NE     262144
#define HIDN   256
#define EDIM   64
#define NHEAD  8
#define FFN    1024
#define ASTART 8192
#define NACT   (NN - ASTART)   // 57344 = 448*128
#define NCH    32768           // edges per chunk (8 chunks)
#define NCHP   (NCH + 128)     // eV GEMM rows incl. straddle slack
#define NCHUNK (NE / NCH)
#define DPC    (NN / NCHUNK)   // expected dsts per chunk = 8192

typedef __attribute__((ext_vector_type(8))) short short8;
typedef __attribute__((ext_vector_type(4))) short short4v;
typedef __attribute__((ext_vector_type(4))) float float4v;
typedef __hip_bfloat16 bf16;

__device__ __forceinline__ float b2f(short s) {
    union { unsigned u; float f; } c;
    c.u = ((unsigned)(unsigned short)s) << 16;
    return c.f;
}
__device__ __forceinline__ short f2b(float f) {
    __hip_bfloat16 h = __float2bfloat16(f);
    return *reinterpret_cast<short*>(&h);
}
// Fast exact-shape GELU: erf via A&S 7.1.26 (|err|<=1.5e-7, below bf16 ulp).
__device__ __forceinline__ float gelu_fast(float v) {
    const float x  = v * 0.70710678118654752f;
    const float ax = fabsf(x);
    const float t  = __builtin_amdgcn_rcpf(1.0f + 0.3275911f * ax);
    const float y  = t * (0.254829592f + t * (-0.284496736f + t * (1.421413741f +
                     t * (-1.453152027f + t * 1.061405429f))));
    const float e  = __expf(-x * x);
    float erf = 1.0f - y * e;
    erf = copysignf(erf, x);
    return 0.5f * v * (1.0f + erf);
}
// async global->LDS 16B per lane; LDS dest = base + lane*16 (wave-uniform base).
__device__ __forceinline__ void gload16(const void* g, void* l) {
    __builtin_amdgcn_global_load_lds(
        (const __attribute__((address_space(1))) void*)(uintptr_t)g,
        (__attribute__((address_space(3))) void*)(unsigned)(uintptr_t)l,
        16, 0, 0);
}

__global__ void convert_kernel(const float* __restrict__ src,
                               bf16* __restrict__ dst, int n) {
    int i = blockIdx.x * 256 + threadIdx.x;
    if (i < n) dst[i] = __float2bfloat16(src[i]);
}
// vectorized variant for large n % 4 == 0
__global__ void convert4_kernel(const float* __restrict__ src,
                                bf16* __restrict__ dst, int n4) {
    int i = blockIdx.x * 256 + threadIdx.x;
    if (i >= n4) return;
    float4v f = *(const float4v*)(src + (size_t)i * 4);
    short4v o;
    #pragma unroll
    for (int j = 0; j < 4; ++j) o[j] = f2b(f[j]);
    *(short4v*)((short*)dst + (size_t)i * 4) = o;
}

// eattr_s[p][:] = bf16(eattr[perm[p]][:]) — one-time sorted-edge gather.
__global__ void gather_kernel(const float* __restrict__ src,
                              const int* __restrict__ perm,
                              bf16* __restrict__ dst) {
    int i = blockIdx.x * 256 + threadIdx.x;
    if (i >= NE * 16) return;
    const int p = i >> 4, j = i & 15;
    const float4v f = *(const float4v*)(src + (size_t)perm[p] * EDIM + j * 4);
    short4v o;
    #pragma unroll
    for (int k = 0; k < 4; ++k) o[k] = f2b(f[k]);
    *(short4v*)((short*)dst + (size_t)p * EDIM + j * 4) = o;
}

// dst[C x R] = src[R x C]^T  (fp32 in, bf16 out); R % 4 == 0.
__global__ void transpose_kernel(const float* __restrict__ src,
                                 bf16* __restrict__ dst, int R, int Cc) {
    int o = blockIdx.x * 256 + threadIdx.x;
    if (o * 4 >= R * Cc) return;
    const int c  = (o * 4) / R;
    const int r0 = (o * 4) - c * R;
    short4v w;
    #pragma unroll
    for (int j = 0; j < 4; ++j)
        w[j] = f2b(src[(size_t)(r0 + j) * Cc + c]);
    *(short4v*)((short*)dst + (size_t)c * R + r0) = w;
}

// ---------------- CSR build (edge_index is constant across layers) ----------
__global__ void hist_kernel(const int* __restrict__ dstI, int* __restrict__ cnt) {
    int i = blockIdx.x * 256 + threadIdx.x;
    if (i < NE) atomicAdd(&cnt[dstI[i]], 1);
}
__global__ void scan1_kernel(const int* __restrict__ cnt, int* __restrict__ rp,
                             int* __restrict__ bsum) {
    __shared__ int s[256];
    int t = threadIdx.x, i = blockIdx.x * 256 + t;
    int v = cnt[i]; s[t] = v; __syncthreads();
    for (int off = 1; off < 256; off <<= 1) {
        int x = (t >= off) ? s[t - off] : 0; __syncthreads();
        s[t] += x; __syncthreads();
    }
    rp[i] = s[t] - v;
    if (t == 255) bsum[blockIdx.x] = s[255];
}
__global__ void scan2_kernel(int* __restrict__ bsum) {
    __shared__ int s[256];
    int t = threadIdx.x; int v = bsum[t]; s[t] = v; __syncthreads();
    for (int off = 1; off < 256; off <<= 1) {
        int x = (t >= off) ? s[t - off] : 0; __syncthreads();
        s[t] += x; __syncthreads();
    }
    bsum[t] = s[t] - v;
}
__global__ void scan3_kernel(int* __restrict__ rp, const int* __restrict__ bsum,
                             int* __restrict__ cursor) {
    int i = blockIdx.x * 256 + threadIdx.x;
    int v = rp[i] + bsum[i >> 8];
    rp[i] = v; cursor[i] = v;
    if (i == 0) rp[NN] = NE;
}
__global__ void scatter_kernel(const int* __restrict__ srcI, const int* __restrict__ dstI,
                               int* __restrict__ cursor, int* __restrict__ perm,
                               int* __restrict__ src_s, int* __restrict__ dst_s) {
    int e = blockIdx.x * 256 + threadIdx.x;
    if (e >= NE) return;
    int d = dstI[e];
    int pos = atomicAdd(&cursor[d], 1);
    perm[pos] = e; src_s[pos] = srcI[e]; dst_s[pos] = d;
}

// ---------------------------------------------------------------------------
// MFMA GEMM: C[M,N] = A[M,K] @ B[K,N] (+bias)(+gelu), C bf16.
// 128x128 tile, BK=32, 4 waves (2x2), wave 64x64 = 4x4 16x16x32 frags.
// AMODE 0 (bf16 A, global_load_lds): 3-deep LDS ring with counted vmcnt.
// AMODE 1/2 (fp32 A via VALU convert + ds_write): proven 2-phase dbuf loop.
// T1 XCD-bijective block remap. Coalesced epilogue via LDS C-tile + short8.
// BT is N x K bf16. M%128==0, N%128==0, K%32==0 (K>=64).
// ---------------------------------------------------------------------------
template<int AMODE, bool DO_GELU>
__global__ __launch_bounds__(256) void gemm_kernel(
    const void* __restrict__ A,
    const bf16* __restrict__ BT,
    const bf16* __restrict__ bias,
    bf16* __restrict__ C,
    int M, int Nn, int K,
    const int* __restrict__ perm, int permN)
{
    constexpr int RING = (AMODE == 0) ? 3 : 2;
    __shared__ __align__(16) short Ls[2 * RING][128 * 32];

    const int gx   = gridDim.x;
    const int nwg  = gx * gridDim.y;
    const int orig = blockIdx.y * gx + blockIdx.x;
    const int q8   = nwg >> 3, r8 = nwg & 7;
    const int xcd  = orig & 7, rk = orig >> 3;
    const int nid  = (xcd < r8 ? xcd * (q8 + 1) : r8 * (q8 + 1) + (xcd - r8) * q8) + rk;
    const int by   = nid / gx;
    const int bx   = nid - by * gx;

    const int t    = threadIdx.x;
    const int wave = t >> 6;
    const int lane = t & 63;
    const int l15  = lane & 15;
    const int quad = lane >> 4;
    const int wm   = (wave & 1) * 64;
    const int wn   = (wave >> 1) * 64;
    const int bm   = by * 128;
    const int bn   = bx * 128;
    const int srow = t >> 2;
    const int sw   = srow & 3;
    const int scolB = ((t & 3) ^ sw) * 8;
    const int scolA = (t & 3) * 8;

    const short* Ab = (const short*)A  + (size_t)(bm + srow) * K + scolB;
    const short* Bb = (const short*)BT + (size_t)(bn + srow) * K + scolB;
    const float* Af0 = nullptr;
    const float* Af1 = nullptr;
    if (AMODE == 1) {
        Af0 = (const float*)A + (size_t)(bm + srow) * K + scolA;
        Af1 = Af0 + (size_t)64 * K;
    } else if (AMODE == 2) {
        int i0 = bm + srow;       if (i0 >= permN) i0 = permN - 1;
        int i1 = bm + 64 + srow;  if (i1 >= permN) i1 = permN - 1;
        const int pr0 = perm[i0];
        const int pr1 = perm[i1];
        Af0 = (const float*)A + (size_t)pr0 * K + scolA;
        Af1 = (const float*)A + (size_t)pr1 * K + scolA;
    }
    const int offW  = wave * 1024;
    const int offTs = (t * 16) ^ (sw << 4);
    const int qs16  = (quad ^ (l15 & 3)) * 16;

    float4v acc[4][4];
    #pragma unroll
    for (int i = 0; i < 4; ++i)
        #pragma unroll
        for (int j = 0; j < 4; ++j) acc[i][j] = (float4v){0.f, 0.f, 0.f, 0.f};

    const int nt = K >> 5;

    auto STAGE = [&](int b, int k0) {
        char* lA = (char*)Ls[b];
        char* lB = (char*)Ls[RING + b];
        if (AMODE == 0) {
            gload16(Ab + k0,                  lA + offW);
            gload16(Ab + (size_t)64 * K + k0, lA + 4096 + offW);
        } else {
            #pragma unroll
            for (int i = 0; i < 2; ++i) {
                const float* s = (i ? Af1 : Af0) + k0;
                float4v f0 = *(const float4v*)s;
                float4v f1 = *(const float4v*)(s + 4);
                short8 w;
                #pragma unroll
                for (int j = 0; j < 4; ++j) { w[j] = f2b(f0[j]); w[4 + j] = f2b(f1[j]); }
                *(short8*)(lA + i * 4096 + offTs) = w;
            }
        }
        gload16(Bb + k0,                  lB + offW);
        gload16(Bb + (size_t)64 * K + k0, lB + 4096 + offW);
    };

    auto COMPUTE = [&](int b) {
        const char* lA = (const char*)Ls[b];
        const char* lB = (const char*)Ls[RING + b];
        short8 afr[4], bfr[4];
        #pragma unroll
        for (int i = 0; i < 4; ++i)
            afr[i] = *(const short8*)(lA + (wm + i * 16 + l15) * 64 + qs16);
        #pragma unroll
        for (int j = 0; j < 4; ++j)
            bfr[j] = *(const short8*)(lB + (wn + j * 16 + l15) * 64 + qs16);
        #pragma unroll
        for (int i = 0; i < 4; ++i)
            #pragma unroll
            for (int j = 0; j < 4; ++j)
                acc[i][j] = __builtin_amdgcn_mfma_f32_16x16x32_bf16(afr[i], bfr[j], acc[i][j], 0, 0, 0);
    };

    if (AMODE == 0) {
        STAGE(0, 0);
        STAGE(1, 32);
        for (int kt = 0; kt < nt - 2; ++kt) {
            asm volatile("s_waitcnt vmcnt(4) lgkmcnt(0)" ::: "memory");
            __builtin_amdgcn_sched_barrier(0);
            __builtin_amdgcn_s_barrier();
            __builtin_amdgcn_sched_barrier(0);
            STAGE((kt + 2) % 3, (kt + 2) * 32);
            COMPUTE(kt % 3);
        }
        asm volatile("s_waitcnt vmcnt(4) lgkmcnt(0)" ::: "memory");
        __builtin_amdgcn_sched_barrier(0);
        __builtin_amdgcn_s_barrier();
        __builtin_amdgcn_sched_barrier(0);
        COMPUTE((nt - 2) % 3);
        asm volatile("s_waitcnt vmcnt(0) lgkmcnt(0)" ::: "memory");
        __builtin_amdgcn_sched_barrier(0);
        __builtin_amdgcn_s_barrier();
        __builtin_amdgcn_sched_barrier(0);
        COMPUTE((nt - 1) % 3);
        __syncthreads();
    } else {
        STAGE(0, 0);
        __syncthreads();
        for (int kt = 0; kt < nt; ++kt) {
            const int cur = kt & 1;
            if (kt + 1 < nt) STAGE(cur ^ 1, (kt + 1) * 32);
            COMPUTE(cur);
            __syncthreads();
        }
    }

    short* Ct = (short*)Ls;
    #pragma unroll
    for (int j = 0; j < 4; ++j) {
        const int col  = wn + j * 16 + l15;
        const int pc   = col ^ (quad << 4);
        const float bv = bias ? b2f(((const short*)bias)[bn + col]) : 0.0f;
        #pragma unroll
        for (int i = 0; i < 4; ++i) {
            const int row0 = wm + i * 16 + quad * 4;
            #pragma unroll
            for (int r = 0; r < 4; ++r) {
                float v = acc[i][j][r] + bv;
                if (DO_GELU) v = gelu_fast(v);
                Ct[(row0 + r) * 128 + pc] = f2b(v);
            }
        }
    }
    __syncthreads();
    #pragma unroll
    for (int it = 0; it < 8; ++it) {
        const int row = wave * 32 + it + ((lane >> 4) << 3);
        const int cs  = (lane & 15) * 8;
        const int pcs = cs ^ (((row >> 2) & 3) << 4);
        short8 w = *(const short8*)&Ct[row * 128 + pcs];
        *(short8*)((short*)C + (size_t)(bm + row) * Nn + bn + cs) = w;
    }
}

// ---------------------------------------------------------------------------
// Fused GEMM + residual + LayerNorm:
//   x[rowbase+r, :] = LN(x[rowbase+r, :] + A[r,:]@B + bias) * sc + bi
// BM=128, BN=256 (full HIDN row -> LN block-local), grid (1, M/128).
// 4 waves: wave w -> rows (w&1)*64.., cols (w>>1)*128.. ; acc[4][8].
// K-loop: proven 2-phase dbuf (A 2x8KB + B 2x16KB = 48KB LDS).
// Epilogue: acc += bias + x; per-row sum/ssq via 16-lane shfl groups +
// LDS cross-wave reduce; normalize; Ct/short8 store in two column halves.
// A bf16 [M x K], BT [256 x K]. M%128==0, K%32==0.
// ---------------------------------------------------------------------------
__global__ __launch_bounds__(256) void gemm_ln_kernel(
    const bf16* __restrict__ A, const bf16* __restrict__ BT,
    const bf16* __restrict__ bias, bf16* __restrict__ x,
    const bf16* __restrict__ sc, const bf16* __restrict__ bi,
    int M, int K, int rowbase)
{
    __shared__ __align__(16) short Ls[24576];    // 48KB
    // slabs: A buf b = Ls + b*4096 ; B buf b = Ls + 8192 + b*8192 (shorts)
    // epilogue: Ct = Ls[0..16383]; rsum/rssq floats at Ls+16384 (1KB each x2)

    const int nwg  = gridDim.y;
    const int orig = blockIdx.y;
    const int q8   = nwg >> 3, r8 = nwg & 7;
    const int xcd  = orig & 7, rk = orig >> 3;
    const int by   = (xcd < r8 ? xcd * (q8 + 1) : r8 * (q8 + 1) + (xcd - r8) * q8) + rk;

    const int t    = threadIdx.x;
    const int wave = t >> 6;
    const int lane = t & 63;
    const int l15  = lane & 15;
    const int quad = lane >> 4;
    const int wm   = (wave & 1) * 64;
    const int wn   = (wave >> 1) * 128;          // column half base
    const int bm   = by * 128;
    const int srow = t >> 2;
    const int sw   = srow & 3;
    const int scol = ((t & 3) ^ sw) * 8;
    const int offW = wave * 1024;
    const int qs16 = (quad ^ (l15 & 3)) * 16;

    const short* Ab = (const short*)A  + (size_t)(bm + srow) * K + scol;
    const short* Bb = (const short*)BT + (size_t)srow * K + scol;

    float4v acc[4][8];
    #pragma unroll
    for (int i = 0; i < 4; ++i)
        #pragma unroll
        for (int j = 0; j < 8; ++j) acc[i][j] = (float4v){0.f, 0.f, 0.f, 0.f};

    const int nt = K >> 5;

    auto STAGE = [&](int b, int k0) {
        char* lA = (char*)Ls + b * 8192;
        char* lB = (char*)Ls + 16384 + b * 16384;
        gload16(Ab + k0,                   lA + offW);
        gload16(Ab + (size_t)64 * K + k0,  lA + 4096 + offW);
        gload16(Bb + k0,                   lB + offW);
        gload16(Bb + (size_t)64 * K + k0,  lB + 4096 + offW);
        gload16(Bb + (size_t)128 * K + k0, lB + 8192 + offW);
        gload16(Bb + (size_t)192 * K + k0, lB + 12288 + offW);
    };

    STAGE(0, 0);
    __syncthreads();
    for (int kt = 0; kt < nt; ++kt) {
        const int cur = kt & 1;
        if (kt + 1 < nt) STAGE(cur ^ 1, (kt + 1) * 32);
        const char* lA = (const char*)Ls + cur * 8192;
        const char* lB = (const char*)Ls + 16384 + cur * 16384;
        short8 afr[4];
        #pragma unroll
        for (int i = 0; i < 4; ++i)
            afr[i] = *(const short8*)(lA + (wm + i * 16 + l15) * 64 + qs16);
        #pragma unroll
        for (int jb = 0; jb < 2; ++jb) {
            short8 bfr[4];
            #pragma unroll
            for (int j2 = 0; j2 < 4; ++j2)
                bfr[j2] = *(const short8*)(lB + (wn + (jb * 4 + j2) * 16 + l15) * 64 + qs16);
            #pragma unroll
            for (int i = 0; i < 4; ++i)
                #pragma unroll
                for (int j2 = 0; j2 < 4; ++j2)
                    acc[i][jb * 4 + j2] = __builtin_amdgcn_mfma_f32_16x16x32_bf16(
                        afr[i], bfr[j2], acc[i][jb * 4 + j2], 0, 0, 0);
        }
        __syncthreads();
    }

    // ---- acc += bias + x (residual); acc now holds LN input v ----
    #pragma unroll
    for (int j = 0; j < 8; ++j) {
        const int gcol = wn + j * 16 + l15;
        const float bv = bias ? b2f(((const short*)bias)[gcol]) : 0.0f;
        #pragma unroll
        for (int i = 0; i < 4; ++i) {
            const int row0 = wm + i * 16 + quad * 4;
            #pragma unroll
            for (int r = 0; r < 4; ++r) {
                const float xv = b2f(((const short*)x)[(size_t)(rowbase + bm + row0 + r) * HIDN + gcol]);
                acc[i][j][r] += bv + xv;
            }
        }
    }

    // ---- per-row stats: lane partial over its 8 cols, 16-lane shfl reduce ----
    float psum[4][4], pssq[4][4];
    #pragma unroll
    for (int i = 0; i < 4; ++i)
        #pragma unroll
        for (int r = 0; r < 4; ++r) {
            float s = 0.f, q = 0.f;
            #pragma unroll
            for (int j = 0; j < 8; ++j) { const float v = acc[i][j][r]; s += v; q += v * v; }
            #pragma unroll
            for (int m = 1; m < 16; m <<= 1) { s += __shfl_xor(s, m); q += __shfl_xor(q, m); }
            psum[i][r] = s; pssq[i][r] = q;
        }

    float* rsum = (float*)((char*)Ls + 32768);   // [2][128]
    float* rssq = rsum + 256;                    // [2][128]
    const int ch = wn >> 7;                      // column half 0/1
    if (l15 == 0) {
        #pragma unroll
        for (int i = 0; i < 4; ++i)
            #pragma unroll
            for (int r = 0; r < 4; ++r) {
                const int row = wm + i * 16 + quad * 4 + r;
                rsum[ch * 128 + row] = psum[i][r];
                rssq[ch * 128 + row] = pssq[i][r];
            }
    }
    __syncthreads();
    float meanv[4][4], rstdv[4][4];
    #pragma unroll
    for (int i = 0; i < 4; ++i)
        #pragma unroll
        for (int r = 0; r < 4; ++r) {
            const int row = wm + i * 16 + quad * 4 + r;
            const float s = rsum[row] + rsum[128 + row];
            const float q = rssq[row] + rssq[128 + row];
            const float mean = s * (1.0f / 256.0f);
            const float var  = fmaxf(q * (1.0f / 256.0f) - mean * mean, 0.0f);
            meanv[i][r] = mean;
            rstdv[i][r] = rsqrtf(var + 1e-5f);
        }
    __syncthreads();    // rsum reads done before Ct overwrites LDS

    // ---- normalize + store via Ct (128x128) in two column halves ----
    short* Ct = (short*)Ls;
    #pragma unroll
    for (int h = 0; h < 2; ++h) {
        if ((wave >> 1) == h) {
            #pragma unroll
            for (int j = 0; j < 8; ++j) {
                const int colh = j * 16 + l15;
                const int pc   = colh ^ (quad << 4);
                const float scv = b2f(((const short*)sc)[h * 128 + colh]);
                const float biv = b2f(((const short*)bi)[h * 128 + colh]);
                #pragma unroll
                for (int i = 0; i < 4; ++i) {
                    const int row0 = wm + i * 16 + quad * 4;
                    #pragma unroll
                    for (int r = 0; r < 4; ++r) {
                        const float v = (acc[i][j][r] - meanv[i][r]) * rstdv[i][r] * scv + biv;
                        Ct[(row0 + r) * 128 + pc] = f2b(v);
                    }
                }
            }
        }
        __syncthreads();
        #pragma unroll
        for (int it = 0; it < 8; ++it) {
            const int row = wave * 32 + it + ((lane >> 4) << 3);
            const int cs  = (lane & 15) * 8;
            const int pcs = cs ^ (((row >> 2) & 3) << 4);
            short8 w = *(const short8*)&Ct[row * 128 + pcs];
            *(short8*)((short*)x + (size_t)(rowbase + bm + row) * HIDN + h * 128 + cs) = w;
        }
        __syncthreads();
    }
}

// One wave per sorted edge pos p: pe = exp(clamp(score)); pbuf[p*8+h] (bf16).
// dmin: skip dsts below (layer-2 rows < ASTART are never read).
__global__ __launch_bounds__(256) void score_kernel(
    const bf16* __restrict__ q, const bf16* __restrict__ k,
    const bf16* __restrict__ eK,
    const int* __restrict__ src_s, const int* __restrict__ dst_s,
    short* __restrict__ pbuf, int e0, int qkstride, int dmin)
{
    const int p = e0 + blockIdx.x * 4 + (threadIdx.x >> 6);
    const int lane = threadIdx.x & 63;
    const int s = src_s[p], d = dst_s[p];
    if (d < dmin) return;
    const int off = lane * 4;

    const short4v qv = *(const short4v*)((const short*)q  + (size_t)d * qkstride + off);
    const short4v kv = *(const short4v*)((const short*)k  + (size_t)s * qkstride + off);
    const short4v ev = *(const short4v*)((const short*)eK + (size_t)(p - e0) * HIDN + off);
    float x = 0.f;
    #pragma unroll
    for (int j = 0; j < 4; ++j) x += b2f(qv[j]) * (b2f(kv[j]) + b2f(ev[j]));
    x += __shfl_xor(x, 1);
    x += __shfl_xor(x, 2);
    x += __shfl_xor(x, 4);
    if ((lane & 7) == 0) {
        const float sc = fminf(fmaxf(x * 0.17677669529663689f, -30.f), 30.f);
        pbuf[(size_t)p * NHEAD + (lane >> 3)] = f2b(expf(sc));
    }
}

// One wave per dst d (owned by chunk containing its CSR start). bf16 out.
// dmin: skip dsts below (layer-2).
__global__ __launch_bounds__(256) void agg_kernel(
    const short* __restrict__ pbuf, const bf16* __restrict__ v,
    const bf16* __restrict__ eV,
    const int* __restrict__ src_s, const int* __restrict__ rp,
    bf16* __restrict__ agg, int e0, int e1x, int dlo, int dmin)
{
    const int d = dlo + blockIdx.x * 4 + (threadIdx.x >> 6);
    const int lane = threadIdx.x & 63;
    if (d < dmin) return;
    const int es = rp[d], ee = rp[d + 1];
    if (es < e0 || es >= e1x) return;
    const int h = lane >> 3, off = lane * 4;

    float a0 = 0.f, a1 = 0.f, a2 = 0.f, a3 = 0.f;
    if (es < ee) {
        float den = 0.f;
        for (int p = es; p < ee; ++p) den += b2f(pbuf[(size_t)p * NHEAD + h]);
        const float rden = 1.0f / den;
        for (int p = es; p < ee; ++p) {
            const float al = b2f(pbuf[(size_t)p * NHEAD + h]) * rden;
            const int s = src_s[p];
            const short4v vv = *(const short4v*)((const short*)v  + (size_t)s * HIDN + off);
            const short4v ev = *(const short4v*)((const short*)eV + (size_t)(p - e0) * HIDN + off);
            a0 += al * (b2f(vv[0]) + b2f(ev[0]));
            a1 += al * (b2f(vv[1]) + b2f(ev[1]));
            a2 += al * (b2f(vv[2]) + b2f(ev[2]));
            a3 += al * (b2f(vv[3]) + b2f(ev[3]));
        }
    }
    short4v o;
    o[0] = f2b(a0); o[1] = f2b(a1); o[2] = f2b(a2); o[3] = f2b(a3);
    *(short4v*)((short*)agg + (size_t)d * HIDN + off) = o;
}

// One wave per row: out[row, 0..6] = h1[row,:] @ w2 + b2  (fp32 out).
__global__ __launch_bounds__(256) void head2_kernel(
    const bf16* __restrict__ h1, const bf16* __restrict__ w2T,
    const bf16* __restrict__ b2, float* __restrict__ out)
{
    const int row = blockIdx.x * 4 + (threadIdx.x >> 6);
    const int lane = threadIdx.x & 63;
    const int off = lane * 4;
    const short4v hv = *(const short4v*)((const short*)h1 + (size_t)row * HIDN + off);
    float hf[4];
    #pragma unroll
    for (int j = 0; j < 4; ++j) hf[j] = b2f(hv[j]);
    float acc[7];
    #pragma unroll
    for (int jc = 0; jc < 7; ++jc) {
        const short4v wv = *(const short4v*)((const short*)w2T + jc * HIDN + off);
        float a = hf[0]*b2f(wv[0]) + hf[1]*b2f(wv[1]) + hf[2]*b2f(wv[2]) + hf[3]*b2f(wv[3]);
        #pragma unroll
        for (int m = 1; m < 64; m <<= 1) a += __shfl_xor(a, m);
        acc[jc] = a;
    }
    if (lane < 7) {
        float r = lane == 0 ? acc[0] : lane == 1 ? acc[1] : lane == 2 ? acc[2] :
                  lane == 3 ? acc[3] : lane == 4 ? acc[4] : lane == 5 ? acc[5] : acc[6];
        out[(size_t)row * 7 + lane] = r + b2f(((const short*)b2)[lane]);
    }
}

extern "C" void kernel_launch(void* const* d_in, const int* in_sizes, int n_in,
                              void* d_out, int out_size, void* d_ws, size_t ws_size,
                              hipStream_t stream)
{
    const float* xin   = (const float*)d_in[0];
    const float* eattr = (const float*)d_in[1];
    const float* Wq    = (const float*)d_in[2];
    const float* Wk    = (const float*)d_in[3];
    const float* Wv    = (const float*)d_in[4];
    const float* WeK   = (const float*)d_in[5];
    const float* WeV   = (const float*)d_in[6];
    const float* Wo    = (const float*)d_in[7];
    const float* ln1s  = (const float*)d_in[8];
    const float* ln1b  = (const float*)d_in[9];
    const float* fw1   = (const float*)d_in[10];
    const float* fb1   = (const float*)d_in[11];
    const float* fw2   = (const float*)d_in[12];
    const float* fb2   = (const float*)d_in[13];
    const float* ln2s  = (const float*)d_in[14];
    const float* ln2b  = (const float*)d_in[15];
    const float* hw1   = (const float*)d_in[16];
    const float* hb1   = (const float*)d_in[17];
    const float* hw2   = (const float*)d_in[18];
    const float* hb2   = (const float*)d_in[19];
    const int*  eidx   = (const int*)d_in[20];
    const int*  srcI   = eidx;
    const int*  dstI   = eidx + NE;

    // ---- workspace carve-up (256B aligned), ~154 MB mandatory ----
    char* base = (char*)d_ws;
    size_t off = 0;
    auto carve = [&](size_t bytes) -> char* {
        char* p = base + off;
        off += (bytes + 255) & ~(size_t)255;
        return p;
    };
    bf16*  x_b    = (bf16*) carve((size_t)NN * HIDN * 2);      // 32 MB persistent
    bf16*  qk_b   = (bf16*) carve((size_t)NN * 2 * HIDN * 2);  // 64 MB fused q|k
    bf16*  v_b    = (bf16*) carve((size_t)NN * HIDN * 2);      // 32 MB
    bf16*  echunk = (bf16*) carve((size_t)NCHP * HIDN * 2);    // 16 MB (also CSR scratch)
    short* pbuf   = (short*)carve((size_t)NE * NHEAD * 2);     //  4 MB (bf16 pe)
    int*   perm   = (int*)  carve((size_t)NE * 4);             //  1 MB
    int*   src_s  = (int*)  carve((size_t)NE * 4);             //  1 MB
    int*   dst_s  = (int*)  carve((size_t)NE * 4);             //  1 MB
    int*   rowp   = (int*)  carve((size_t)(NN + 1) * 4);       // .25 MB
    bf16*  WqkT   = (bf16*) carve((size_t)2 * HIDN * HIDN * 2);
    bf16*  WvT    = (bf16*) carve((size_t)HIDN * HIDN * 2);
    bf16*  WoT    = (bf16*) carve((size_t)HIDN * HIDN * 2);
    bf16*  WeKT   = (bf16*) carve((size_t)HIDN * EDIM * 2);
    bf16*  WeVT   = (bf16*) carve((size_t)HIDN * EDIM * 2);
    bf16*  W1T    = (bf16*) carve((size_t)FFN * HIDN * 2);
    bf16*  W2T    = (bf16*) carve((size_t)HIDN * FFN * 2);
    bf16*  HW1T   = (bf16*) carve((size_t)HIDN * HIDN * 2);
    bf16*  HW2T   = (bf16*) carve((size_t)8 * HIDN * 2);
    bf16*  c_ln1s = (bf16*) carve((size_t)2 * HIDN * 2);
    bf16*  c_ln1b = (bf16*) carve((size_t)2 * HIDN * 2);
    bf16*  c_ln2s = (bf16*) carve((size_t)2 * HIDN * 2);
    bf16*  c_ln2b = (bf16*) carve((size_t)2 * HIDN * 2);
    bf16*  c_fb1  = (bf16*) carve((size_t)2 * FFN * 2);
    bf16*  c_fb2  = (bf16*) carve((size_t)2 * HIDN * 2);
    bf16*  c_hb1  = (bf16*) carve((size_t)HIDN * 2);
    bf16*  c_hb2  = (bf16*) carve((size_t)16 * 2);
    const size_t off_mand = off;
    bf16*  eattr_s = (bf16*) carve((size_t)(NE + 128) * EDIM * 2);
    const bool eg = (off <= ws_size);
    if (off_mand > ws_size) return;

    // CSR build scratch inside echunk (dead until layer loop):
    int* cnt    = (int*)echunk;
    int* cursor = cnt + NN;
    int* bsum   = cursor + NN;
    // Phase aliases: qk dead during agg phase -> bf16 agg overlays qk_b;
    // qk dead in FFN -> hid.
    bf16*  agg_b  = qk_b;
    bf16*  hid    = qk_b;

    const int TB = 256;
    #define GRID1(n) dim3(((n) + TB - 1) / TB)

    convert4_kernel<<<GRID1(NN * HIDN / 4), TB, 0, stream>>>(xin, x_b, NN * HIDN / 4);
    convert_kernel<<<GRID1(2 * HIDN), TB, 0, stream>>>(ln1s, c_ln1s, 2 * HIDN);
    convert_kernel<<<GRID1(2 * HIDN), TB, 0, stream>>>(ln1b, c_ln1b, 2 * HIDN);
    convert_kernel<<<GRID1(2 * HIDN), TB, 0, stream>>>(ln2s, c_ln2s, 2 * HIDN);
    convert_kernel<<<GRID1(2 * HIDN), TB, 0, stream>>>(ln2b, c_ln2b, 2 * HIDN);
    convert_kernel<<<GRID1(2 * FFN), TB, 0, stream>>>(fb1, c_fb1, 2 * FFN);
    convert_kernel<<<GRID1(2 * HIDN), TB, 0, stream>>>(fb2, c_fb2, 2 * HIDN);
    convert_kernel<<<GRID1(HIDN), TB, 0, stream>>>(hb1, c_hb1, HIDN);
    convert_kernel<<<1, TB, 0, stream>>>(hb2, c_hb2, 7);
    transpose_kernel<<<GRID1(HIDN * HIDN / 4), TB, 0, stream>>>(hw1, HW1T, HIDN, HIDN);
    transpose_kernel<<<GRID1(HIDN * 7 / 4), TB, 0, stream>>>(hw2, HW2T, HIDN, 7);

    // ---- CSR build (once) ----
    hipMemsetAsync(cnt, 0, (size_t)NN * 4, stream);
    hist_kernel<<<GRID1(NE), TB, 0, stream>>>(dstI, cnt);
    scan1_kernel<<<NN / 256, 256, 0, stream>>>(cnt, rowp, bsum);
    scan2_kernel<<<1, 256, 0, stream>>>(bsum);
    scan3_kernel<<<NN / 256, 256, 0, stream>>>(rowp, bsum, cursor);
    scatter_kernel<<<GRID1(NE), TB, 0, stream>>>(srcI, dstI, cursor, perm, src_s, dst_s);
    if (eg) gather_kernel<<<GRID1(NE * 16), TB, 0, stream>>>(eattr, perm, eattr_s);

    for (int l = 0; l < 2; ++l) {
        const int dmin = l ? ASTART : 0;       // layer-2: rows < ASTART dead after attention input
        const int rs   = l ? ASTART : 0;       // FFN/out-proj row range start
        const int rch  = (NN - rs) / 2;        // 32768 or 28672 (both %128==0)

        transpose_kernel<<<GRID1(HIDN * HIDN / 4), TB, 0, stream>>>(Wq + (size_t)l*HIDN*HIDN, WqkT, HIDN, HIDN);
        transpose_kernel<<<GRID1(HIDN * HIDN / 4), TB, 0, stream>>>(Wk + (size_t)l*HIDN*HIDN, WqkT + (size_t)HIDN*HIDN, HIDN, HIDN);
        transpose_kernel<<<GRID1(HIDN * HIDN / 4), TB, 0, stream>>>(Wv + (size_t)l*HIDN*HIDN, WvT, HIDN, HIDN);
        transpose_kernel<<<GRID1(EDIM * HIDN / 4), TB, 0, stream>>>(WeK + (size_t)l*EDIM*HIDN, WeKT, EDIM, HIDN);
        transpose_kernel<<<GRID1(EDIM * HIDN / 4), TB, 0, stream>>>(WeV + (size_t)l*EDIM*HIDN, WeVT, EDIM, HIDN);
        transpose_kernel<<<GRID1(HIDN * HIDN / 4), TB, 0, stream>>>(Wo + (size_t)l*HIDN*HIDN, WoT, HIDN, HIDN);
        transpose_kernel<<<GRID1(HIDN * FFN / 4),  TB, 0, stream>>>(fw1 + (size_t)l*HIDN*FFN, W1T, HIDN, FFN);
        transpose_kernel<<<GRID1(FFN * HIDN / 4),  TB, 0, stream>>>(fw2 + (size_t)l*FFN*HIDN, W2T, FFN, HIDN);

        // fused q|k projection (N=512) + separate v projection
        gemm_kernel<0, false><<<dim3((2*HIDN)/128, NN/128), TB, 0, stream>>>(x_b, WqkT, nullptr, qk_b, NN, 2*HIDN, HIDN, nullptr, 0);
        gemm_kernel<0, false><<<dim3(HIDN/128, NN/128), TB, 0, stream>>>(x_b, WvT, nullptr, v_b, NN, HIDN, HIDN, nullptr, 0);

        // score phase
        for (int c = 0; c < NCHUNK; ++c) {
            if (eg)
                gemm_kernel<0, false><<<dim3(HIDN/128, NCH/128), TB, 0, stream>>>(
                    eattr_s + (size_t)c * NCH * EDIM, WeKT, nullptr, echunk, NCH, HIDN, EDIM, nullptr, 0);
            else
                gemm_kernel<2, false><<<dim3(HIDN/128, NCH/128), TB, 0, stream>>>(
                    eattr, WeKT, nullptr, echunk, NCH, HIDN, EDIM, perm + (size_t)c * NCH, NE - c * NCH);
            score_kernel<<<NCH / 4, TB, 0, stream>>>(qk_b, qk_b + HIDN, echunk, src_s, dst_s, pbuf, c * NCH, 2 * HIDN, dmin);
        }

        // agg phase (bf16 agg overlays dead qk)
        for (int c = 0; c < NCHUNK; ++c) {
            if (eg)
                gemm_kernel<0, false><<<dim3(HIDN/128, NCHP/128), TB, 0, stream>>>(
                    eattr_s + (size_t)c * NCH * EDIM, WeVT, nullptr, echunk, NCHP, HIDN, EDIM, nullptr, 0);
            else
                gemm_kernel<2, false><<<dim3(HIDN/128, NCHP/128), TB, 0, stream>>>(
                    eattr, WeVT, nullptr, echunk, NCHP, HIDN, EDIM, perm + (size_t)c * NCH, NE - c * NCH);
            const int dlo = (c == 0) ? 0 : (c - 1) * DPC;
            const int dhi = (c == NCHUNK - 1) ? NN : (c + 2) * DPC;
            const int e1x = (c == NCHUNK - 1) ? NE + 1 : (c + 1) * NCH;
            agg_kernel<<<(dhi - dlo) / 4, TB, 0, stream>>>(
                pbuf, v_b, echunk, src_s, rowp, agg_b, c * NCH, e1x, dlo, dmin);
        }

        // fused out-proj + residual + LN1 (x in place), rows >= rs
        gemm_ln_kernel<<<dim3(1, (NN - rs)/128), TB, 0, stream>>>(
            agg_b + (size_t)rs * HIDN, WoT, nullptr, x_b,
            c_ln1s + (size_t)l * HIDN, c_ln1b + (size_t)l * HIDN, NN - rs, HIDN, rs);

        // FFN: FFN1 (gelu) -> hid; fused FFN2 + residual + LN2
        for (int r0 = rs; r0 < NN; r0 += rch) {
            gemm_kernel<0, true ><<<dim3(FFN/128, rch/128), TB, 0, stream>>>(
                x_b + (size_t)r0 * HIDN, W1T, c_fb1 + (size_t)l * FFN, hid, rch, FFN, HIDN, nullptr, 0);
            gemm_ln_kernel<<<dim3(1, rch/128), TB, 0, stream>>>(
                hid, W2T, c_fb2 + (size_t)l * HIDN, x_b,
                c_ln2s + (size_t)l * HIDN, c_ln2b + (size_t)l * HIDN, rch, FFN, r0);
        }
    }

    gemm_kernel<0, true><<<dim3(HIDN/128, NACT/128), TB, 0, stream>>>(
        x_b + (size_t)ASTART * HIDN, HW1T, c_hb1, hid, NACT, HIDN, HIDN, nullptr, 0);
    head2_kernel<<<NACT / 4, TB, 0, stream>>>(hid, HW2T, c_hb2, (float*)d_out);
}

// Round 11
// 1443.508 us; speedup vs baseline: 1.0441x; 1.0441x over previous
//
#include <hip/hip_runtime.h>
#include <hip/hip_bf16.h>
#include <math.h>

// Problem constants (fixed by setup_inputs). All inputs/output are fp32
// (established round 5). Internal compute: bf16 MFMA + fp32 accumulation.
#define NN     65536
#define NE     262144
#define HIDN   256
#define EDIM   64
#define NHEAD  8
#define FFN    1024
#define ASTART 8192
#define NACT   (NN - ASTART)   // 57344 = 448*128
#define NCH    32768           // edges per chunk (8 chunks)
#define NCHP   (NCH + 128)     // eV GEMM rows incl. straddle slack
#define NCHUNK (NE / NCH)
#define DPC    (NN / NCHUNK)   // expected dsts per chunk = 8192

typedef __attribute__((ext_vector_type(8))) short short8;
typedef __attribute__((ext_vector_type(4))) short short4v;
typedef __attribute__((ext_vector_type(4))) float float4v;
typedef __hip_bfloat16 bf16;

__device__ __forceinline__ float b2f(short s) {
    union { unsigned u; float f; } c;
    c.u = ((unsigned)(unsigned short)s) << 16;
    return c.f;
}
__device__ __forceinline__ short f2b(float f) {
    __hip_bfloat16 h = __float2bfloat16(f);
    return *reinterpret_cast<short*>(&h);
}
// Fast exact-shape GELU: erf via A&S 7.1.26 (|err|<=1.5e-7, below bf16 ulp).
__device__ __forceinline__ float gelu_fast(float v) {
    const float x  = v * 0.70710678118654752f;
    const float ax = fabsf(x);
    const float t  = __builtin_amdgcn_rcpf(1.0f + 0.3275911f * ax);
    const float y  = t * (0.254829592f + t * (-0.284496736f + t * (1.421413741f +
                     t * (-1.453152027f + t * 1.061405429f))));
    const float e  = __expf(-x * x);
    float erf = 1.0f - y * e;
    erf = copysignf(erf, x);
    return 0.5f * v * (1.0f + erf);
}
// async global->LDS 16B per lane; LDS dest = base + lane*16 (wave-uniform base).
__device__ __forceinline__ void gload16(const void* g, void* l) {
    __builtin_amdgcn_global_load_lds(
        (const __attribute__((address_space(1))) void*)(uintptr_t)g,
        (__attribute__((address_space(3))) void*)(unsigned)(uintptr_t)l,
        16, 0, 0);
}

__global__ void convert_kernel(const float* __restrict__ src,
                               bf16* __restrict__ dst, int n) {
    int i = blockIdx.x * 256 + threadIdx.x;
    if (i < n) dst[i] = __float2bfloat16(src[i]);
}
// vectorized variant for large n % 4 == 0
__global__ void convert4_kernel(const float* __restrict__ src,
                                bf16* __restrict__ dst, int n4) {
    int i = blockIdx.x * 256 + threadIdx.x;
    if (i >= n4) return;
    float4v f = *(const float4v*)(src + (size_t)i * 4);
    short4v o;
    #pragma unroll
    for (int j = 0; j < 4; ++j) o[j] = f2b(f[j]);
    *(short4v*)((short*)dst + (size_t)i * 4) = o;
}

// eattr_s[p][:] = bf16(eattr[perm[p]][:]) — one-time sorted-edge gather.
__global__ void gather_kernel(const float* __restrict__ src,
                              const int* __restrict__ perm,
                              bf16* __restrict__ dst) {
    int i = blockIdx.x * 256 + threadIdx.x;
    if (i >= NE * 16) return;
    const int p = i >> 4, j = i & 15;
    const float4v f = *(const float4v*)(src + (size_t)perm[p] * EDIM + j * 4);
    short4v o;
    #pragma unroll
    for (int k = 0; k < 4; ++k) o[k] = f2b(f[k]);
    *(short4v*)((short*)dst + (size_t)p * EDIM + j * 4) = o;
}

// dst[C x R] = src[R x C]^T  (fp32 in, bf16 out); R % 4 == 0.
__global__ void transpose_kernel(const float* __restrict__ src,
                                 bf16* __restrict__ dst, int R, int Cc) {
    int o = blockIdx.x * 256 + threadIdx.x;
    if (o * 4 >= R * Cc) return;
    const int c  = (o * 4) / R;
    const int r0 = (o * 4) - c * R;
    short4v w;
    #pragma unroll
    for (int j = 0; j < 4; ++j)
        w[j] = f2b(src[(size_t)(r0 + j) * Cc + c]);
    *(short4v*)((short*)dst + (size_t)c * R + r0) = w;
}

// ---------------- CSR build (edge_index is constant across layers) ----------
__global__ void hist_kernel(const int* __restrict__ dstI, int* __restrict__ cnt) {
    int i = blockIdx.x * 256 + threadIdx.x;
    if (i < NE) atomicAdd(&cnt[dstI[i]], 1);
}
__global__ void scan1_kernel(const int* __restrict__ cnt, int* __restrict__ rp,
                             int* __restrict__ bsum) {
    __shared__ int s[256];
    int t = threadIdx.x, i = blockIdx.x * 256 + t;
    int v = cnt[i]; s[t] = v; __syncthreads();
    for (int off = 1; off < 256; off <<= 1) {
        int x = (t >= off) ? s[t - off] : 0; __syncthreads();
        s[t] += x; __syncthreads();
    }
    rp[i] = s[t] - v;
    if (t == 255) bsum[blockIdx.x] = s[255];
}
__global__ void scan2_kernel(int* __restrict__ bsum) {
    __shared__ int s[256];
    int t = threadIdx.x; int v = bsum[t]; s[t] = v; __syncthreads();
    for (int off = 1; off < 256; off <<= 1) {
        int x = (t >= off) ? s[t - off] : 0; __syncthreads();
        s[t] += x; __syncthreads();
    }
    bsum[t] = s[t] - v;
}
__global__ void scan3_kernel(int* __restrict__ rp, const int* __restrict__ bsum,
                             int* __restrict__ cursor) {
    int i = blockIdx.x * 256 + threadIdx.x;
    int v = rp[i] + bsum[i >> 8];
    rp[i] = v; cursor[i] = v;
    if (i == 0) rp[NN] = NE;
}
__global__ void scatter_kernel(const int* __restrict__ srcI, const int* __restrict__ dstI,
                               int* __restrict__ cursor, int* __restrict__ perm,
                               int* __restrict__ src_s, int* __restrict__ dst_s) {
    int e = blockIdx.x * 256 + threadIdx.x;
    if (e >= NE) return;
    int d = dstI[e];
    int pos = atomicAdd(&cursor[d], 1);
    perm[pos] = e; src_s[pos] = srcI[e]; dst_s[pos] = d;
}

// ---------------------------------------------------------------------------
// MFMA GEMM: C[M,N] = A[M,K] @ B[K,N] (+bias)(+gelu), C bf16.
// 128x128 tile, BK=32, 4 waves (2x2), wave 64x64 = 4x4 16x16x32 frags.
// AMODE 0 (bf16 A, global_load_lds): 3-deep LDS ring with counted vmcnt.
// AMODE 1/2 (fp32 A via VALU convert + ds_write): proven 2-phase dbuf loop.
// T1 XCD-bijective block remap. Coalesced epilogue via LDS C-tile + short8.
// BT is N x K bf16. M%128==0, N%128==0, K%32==0 (K>=64).
// ---------------------------------------------------------------------------
template<int AMODE, bool DO_GELU>
__global__ __launch_bounds__(256) void gemm_kernel(
    const void* __restrict__ A,
    const bf16* __restrict__ BT,
    const bf16* __restrict__ bias,
    bf16* __restrict__ C,
    int M, int Nn, int K,
    const int* __restrict__ perm, int permN)
{
    constexpr int RING = (AMODE == 0) ? 3 : 2;
    __shared__ __align__(16) short Ls[2 * RING][128 * 32];

    const int gx   = gridDim.x;
    const int nwg  = gx * gridDim.y;
    const int orig = blockIdx.y * gx + blockIdx.x;
    const int q8   = nwg >> 3, r8 = nwg & 7;
    const int xcd  = orig & 7, rk = orig >> 3;
    const int nid  = (xcd < r8 ? xcd * (q8 + 1) : r8 * (q8 + 1) + (xcd - r8) * q8) + rk;
    const int by   = nid / gx;
    const int bx   = nid - by * gx;

    const int t    = threadIdx.x;
    const int wave = t >> 6;
    const int lane = t & 63;
    const int l15  = lane & 15;
    const int quad = lane >> 4;
    const int wm   = (wave & 1) * 64;
    const int wn   = (wave >> 1) * 64;
    const int bm   = by * 128;
    const int bn   = bx * 128;
    const int srow = t >> 2;
    const int sw   = srow & 3;
    const int scolB = ((t & 3) ^ sw) * 8;
    const int scolA = (t & 3) * 8;

    const short* Ab = (const short*)A  + (size_t)(bm + srow) * K + scolB;
    const short* Bb = (const short*)BT + (size_t)(bn + srow) * K + scolB;
    const float* Af0 = nullptr;
    const float* Af1 = nullptr;
    if (AMODE == 1) {
        Af0 = (const float*)A + (size_t)(bm + srow) * K + scolA;
        Af1 = Af0 + (size_t)64 * K;
    } else if (AMODE == 2) {
        int i0 = bm + srow;       if (i0 >= permN) i0 = permN - 1;
        int i1 = bm + 64 + srow;  if (i1 >= permN) i1 = permN - 1;
        const int pr0 = perm[i0];
        const int pr1 = perm[i1];
        Af0 = (const float*)A + (size_t)pr0 * K + scolA;
        Af1 = (const float*)A + (size_t)pr1 * K + scolA;
    }
    const int offW  = wave * 1024;
    const int offTs = (t * 16) ^ (sw << 4);
    const int qs16  = (quad ^ (l15 & 3)) * 16;

    float4v acc[4][4];
    #pragma unroll
    for (int i = 0; i < 4; ++i)
        #pragma unroll
        for (int j = 0; j < 4; ++j) acc[i][j] = (float4v){0.f, 0.f, 0.f, 0.f};

    const int nt = K >> 5;

    auto STAGE = [&](int b, int k0) {
        char* lA = (char*)Ls[b];
        char* lB = (char*)Ls[RING + b];
        if (AMODE == 0) {
            gload16(Ab + k0,                  lA + offW);
            gload16(Ab + (size_t)64 * K + k0, lA + 4096 + offW);
        } else {
            #pragma unroll
            for (int i = 0; i < 2; ++i) {
                const float* s = (i ? Af1 : Af0) + k0;
                float4v f0 = *(const float4v*)s;
                float4v f1 = *(const float4v*)(s + 4);
                short8 w;
                #pragma unroll
                for (int j = 0; j < 4; ++j) { w[j] = f2b(f0[j]); w[4 + j] = f2b(f1[j]); }
                *(short8*)(lA + i * 4096 + offTs) = w;
            }
        }
        gload16(Bb + k0,                  lB + offW);
        gload16(Bb + (size_t)64 * K + k0, lB + 4096 + offW);
    };

    auto COMPUTE = [&](int b) {
        const char* lA = (const char*)Ls[b];
        const char* lB = (const char*)Ls[RING + b];
        short8 afr[4], bfr[4];
        #pragma unroll
        for (int i = 0; i < 4; ++i)
            afr[i] = *(const short8*)(lA + (wm + i * 16 + l15) * 64 + qs16);
        #pragma unroll
        for (int j = 0; j < 4; ++j)
            bfr[j] = *(const short8*)(lB + (wn + j * 16 + l15) * 64 + qs16);
        #pragma unroll
        for (int i = 0; i < 4; ++i)
            #pragma unroll
            for (int j = 0; j < 4; ++j)
                acc[i][j] = __builtin_amdgcn_mfma_f32_16x16x32_bf16(afr[i], bfr[j], acc[i][j], 0, 0, 0);
    };

    if (AMODE == 0) {
        STAGE(0, 0);
        STAGE(1, 32);
        for (int kt = 0; kt < nt - 2; ++kt) {
            asm volatile("s_waitcnt vmcnt(4) lgkmcnt(0)" ::: "memory");
            __builtin_amdgcn_sched_barrier(0);
            __builtin_amdgcn_s_barrier();
            __builtin_amdgcn_sched_barrier(0);
            STAGE((kt + 2) % 3, (kt + 2) * 32);
            COMPUTE(kt % 3);
        }
        asm volatile("s_waitcnt vmcnt(4) lgkmcnt(0)" ::: "memory");
        __builtin_amdgcn_sched_barrier(0);
        __builtin_amdgcn_s_barrier();
        __builtin_amdgcn_sched_barrier(0);
        COMPUTE((nt - 2) % 3);
        asm volatile("s_waitcnt vmcnt(0) lgkmcnt(0)" ::: "memory");
        __builtin_amdgcn_sched_barrier(0);
        __builtin_amdgcn_s_barrier();
        __builtin_amdgcn_sched_barrier(0);
        COMPUTE((nt - 1) % 3);
        __syncthreads();
    } else {
        STAGE(0, 0);
        __syncthreads();
        for (int kt = 0; kt < nt; ++kt) {
            const int cur = kt & 1;
            if (kt + 1 < nt) STAGE(cur ^ 1, (kt + 1) * 32);
            COMPUTE(cur);
            __syncthreads();
        }
    }

    short* Ct = (short*)Ls;
    #pragma unroll
    for (int j = 0; j < 4; ++j) {
        const int col  = wn + j * 16 + l15;
        const int pc   = col ^ (quad << 4);
        const float bv = bias ? b2f(((const short*)bias)[bn + col]) : 0.0f;
        #pragma unroll
        for (int i = 0; i < 4; ++i) {
            const int row0 = wm + i * 16 + quad * 4;
            #pragma unroll
            for (int r = 0; r < 4; ++r) {
                float v = acc[i][j][r] + bv;
                if (DO_GELU) v = gelu_fast(v);
                Ct[(row0 + r) * 128 + pc] = f2b(v);
            }
        }
    }
    __syncthreads();
    #pragma unroll
    for (int it = 0; it < 8; ++it) {
        const int row = wave * 32 + it + ((lane >> 4) << 3);
        const int cs  = (lane & 15) * 8;
        const int pcs = cs ^ (((row >> 2) & 3) << 4);
        short8 w = *(const short8*)&Ct[row * 128 + pcs];
        *(short8*)((short*)C + (size_t)(bm + row) * Nn + bn + cs) = w;
    }
}

// One wave per sorted edge pos p: pe = exp(clamp(score)); pbuf[p*8+h] (bf16).
// dmin: skip dsts below (layer-2 rows < ASTART are never read).
__global__ __launch_bounds__(256) void score_kernel(
    const bf16* __restrict__ q, const bf16* __restrict__ k,
    const bf16* __restrict__ eK,
    const int* __restrict__ src_s, const int* __restrict__ dst_s,
    short* __restrict__ pbuf, int e0, int qkstride, int dmin)
{
    const int p = e0 + blockIdx.x * 4 + (threadIdx.x >> 6);
    const int lane = threadIdx.x & 63;
    const int s = src_s[p], d = dst_s[p];
    if (d < dmin) return;
    const int off = lane * 4;

    const short4v qv = *(const short4v*)((const short*)q  + (size_t)d * qkstride + off);
    const short4v kv = *(const short4v*)((const short*)k  + (size_t)s * qkstride + off);
    const short4v ev = *(const short4v*)((const short*)eK + (size_t)(p - e0) * HIDN + off);
    float x = 0.f;
    #pragma unroll
    for (int j = 0; j < 4; ++j) x += b2f(qv[j]) * (b2f(kv[j]) + b2f(ev[j]));
    x += __shfl_xor(x, 1);
    x += __shfl_xor(x, 2);
    x += __shfl_xor(x, 4);
    if ((lane & 7) == 0) {
        const float sc = fminf(fmaxf(x * 0.17677669529663689f, -30.f), 30.f);
        pbuf[(size_t)p * NHEAD + (lane >> 3)] = f2b(expf(sc));
    }
}

// One wave per dst d (owned by chunk containing its CSR start). bf16 out.
// dmin: skip dsts below (layer-2).
__global__ __launch_bounds__(256) void agg_kernel(
    const short* __restrict__ pbuf, const bf16* __restrict__ v,
    const bf16* __restrict__ eV,
    const int* __restrict__ src_s, const int* __restrict__ rp,
    bf16* __restrict__ agg, int e0, int e1x, int dlo, int dmin)
{
    const int d = dlo + blockIdx.x * 4 + (threadIdx.x >> 6);
    const int lane = threadIdx.x & 63;
    if (d < dmin) return;
    const int es = rp[d], ee = rp[d + 1];
    if (es < e0 || es >= e1x) return;
    const int h = lane >> 3, off = lane * 4;

    float a0 = 0.f, a1 = 0.f, a2 = 0.f, a3 = 0.f;
    if (es < ee) {
        float den = 0.f;
        for (int p = es; p < ee; ++p) den += b2f(pbuf[(size_t)p * NHEAD + h]);
        const float rden = 1.0f / den;
        for (int p = es; p < ee; ++p) {
            const float al = b2f(pbuf[(size_t)p * NHEAD + h]) * rden;
            const int s = src_s[p];
            const short4v vv = *(const short4v*)((const short*)v  + (size_t)s * HIDN + off);
            const short4v ev = *(const short4v*)((const short*)eV + (size_t)(p - e0) * HIDN + off);
            a0 += al * (b2f(vv[0]) + b2f(ev[0]));
            a1 += al * (b2f(vv[1]) + b2f(ev[1]));
            a2 += al * (b2f(vv[2]) + b2f(ev[2]));
            a3 += al * (b2f(vv[3]) + b2f(ev[3]));
        }
    }
    short4v o;
    o[0] = f2b(a0); o[1] = f2b(a1); o[2] = f2b(a2); o[3] = f2b(a3);
    *(short4v*)((short*)agg + (size_t)d * HIDN + off) = o;
}

// One wave per row r in [r0, ...): x = LN(x + t)*s + b (in place, bf16).
__global__ __launch_bounds__(256) void ln_kernel(
    bf16* __restrict__ x, const bf16* __restrict__ t,
    const bf16* __restrict__ sc, const bf16* __restrict__ bi, int r0)
{
    const int row = r0 + blockIdx.x * 4 + (threadIdx.x >> 6);
    const int lane = threadIdx.x & 63;
    const size_t base = (size_t)row * HIDN + lane * 4;
    const size_t tbase = (size_t)(row - r0) * HIDN + lane * 4;
    const short4v xv = *(const short4v*)((const short*)x + base);
    const short4v tv = *(const short4v*)((const short*)t + tbase);
    float v[4];
    #pragma unroll
    for (int j = 0; j < 4; ++j) v[j] = b2f(xv[j]) + b2f(tv[j]);
    float sum = v[0] + v[1] + v[2] + v[3];
    float ssq = v[0]*v[0] + v[1]*v[1] + v[2]*v[2] + v[3]*v[3];
    #pragma unroll
    for (int m = 1; m < 64; m <<= 1) { sum += __shfl_xor(sum, m); ssq += __shfl_xor(ssq, m); }
    const float mean = sum * (1.0f / 256.0f);
    const float var  = fmaxf(ssq * (1.0f / 256.0f) - mean * mean, 0.0f);
    const float rstd = rsqrtf(var + 1e-5f);
    const short4v sv = *(const short4v*)((const short*)sc + lane * 4);
    const short4v bv = *(const short4v*)((const short*)bi + lane * 4);
    short4v out;
    #pragma unroll
    for (int j = 0; j < 4; ++j)
        out[j] = f2b((v[j] - mean) * rstd * b2f(sv[j]) + b2f(bv[j]));
    *(short4v*)((short*)x + base) = out;
}

// One wave per row: out[row, 0..6] = h1[row,:] @ w2 + b2  (fp32 out).
__global__ __launch_bounds__(256) void head2_kernel(
    const bf16* __restrict__ h1, const bf16* __restrict__ w2T,
    const bf16* __restrict__ b2, float* __restrict__ out)
{
    const int row = blockIdx.x * 4 + (threadIdx.x >> 6);
    const int lane = threadIdx.x & 63;
    const int off = lane * 4;
    const short4v hv = *(const short4v*)((const short*)h1 + (size_t)row * HIDN + off);
    float hf[4];
    #pragma unroll
    for (int j = 0; j < 4; ++j) hf[j] = b2f(hv[j]);
    float acc[7];
    #pragma unroll
    for (int jc = 0; jc < 7; ++jc) {
        const short4v wv = *(const short4v*)((const short*)w2T + jc * HIDN + off);
        float a = hf[0]*b2f(wv[0]) + hf[1]*b2f(wv[1]) + hf[2]*b2f(wv[2]) + hf[3]*b2f(wv[3]);
        #pragma unroll
        for (int m = 1; m < 64; m <<= 1) a += __shfl_xor(a, m);
        acc[jc] = a;
    }
    if (lane < 7) {
        float r = lane == 0 ? acc[0] : lane == 1 ? acc[1] : lane == 2 ? acc[2] :
                  lane == 3 ? acc[3] : lane == 4 ? acc[4] : lane == 5 ? acc[5] : acc[6];
        out[(size_t)row * 7 + lane] = r + b2f(((const short*)b2)[lane]);
    }
}

extern "C" void kernel_launch(void* const* d_in, const int* in_sizes, int n_in,
                              void* d_out, int out_size, void* d_ws, size_t ws_size,
                              hipStream_t stream)
{
    const float* xin   = (const float*)d_in[0];
    const float* eattr = (const float*)d_in[1];
    const float* Wq    = (const float*)d_in[2];
    const float* Wk    = (const float*)d_in[3];
    const float* Wv    = (const float*)d_in[4];
    const float* WeK   = (const float*)d_in[5];
    const float* WeV   = (const float*)d_in[6];
    const float* Wo    = (const float*)d_in[7];
    const float* ln1s  = (const float*)d_in[8];
    const float* ln1b  = (const float*)d_in[9];
    const float* fw1   = (const float*)d_in[10];
    const float* fb1   = (const float*)d_in[11];
    const float* fw2   = (const float*)d_in[12];
    const float* fb2   = (const float*)d_in[13];
    const float* ln2s  = (const float*)d_in[14];
    const float* ln2b  = (const float*)d_in[15];
    const float* hw1   = (const float*)d_in[16];
    const float* hb1   = (const float*)d_in[17];
    const float* hw2   = (const float*)d_in[18];
    const float* hb2   = (const float*)d_in[19];
    const int*  eidx   = (const int*)d_in[20];
    const int*  srcI   = eidx;
    const int*  dstI   = eidx + NE;

    // ---- workspace carve-up (256B aligned), ~154 MB mandatory ----
    char* base = (char*)d_ws;
    size_t off = 0;
    auto carve = [&](size_t bytes) -> char* {
        char* p = base + off;
        off += (bytes + 255) & ~(size_t)255;
        return p;
    };
    bf16*  x_b    = (bf16*) carve((size_t)NN * HIDN * 2);      // 32 MB persistent
    bf16*  qk_b   = (bf16*) carve((size_t)NN * 2 * HIDN * 2);  // 64 MB fused q|k
    bf16*  v_b    = (bf16*) carve((size_t)NN * HIDN * 2);      // 32 MB
    bf16*  echunk = (bf16*) carve((size_t)NCHP * HIDN * 2);    // 16 MB (also CSR scratch)
    short* pbuf   = (short*)carve((size_t)NE * NHEAD * 2);     //  4 MB (bf16 pe)
    int*   perm   = (int*)  carve((size_t)NE * 4);             //  1 MB
    int*   src_s  = (int*)  carve((size_t)NE * 4);             //  1 MB
    int*   dst_s  = (int*)  carve((size_t)NE * 4);             //  1 MB
    int*   rowp   = (int*)  carve((size_t)(NN + 1) * 4);       // .25 MB
    bf16*  WqkT   = (bf16*) carve((size_t)2 * HIDN * HIDN * 2);
    bf16*  WvT    = (bf16*) carve((size_t)HIDN * HIDN * 2);
    bf16*  WoT    = (bf16*) carve((size_t)HIDN * HIDN * 2);
    bf16*  WeKT   = (bf16*) carve((size_t)HIDN * EDIM * 2);
    bf16*  WeVT   = (bf16*) carve((size_t)HIDN * EDIM * 2);
    bf16*  W1T    = (bf16*) carve((size_t)FFN * HIDN * 2);
    bf16*  W2T    = (bf16*) carve((size_t)HIDN * FFN * 2);
    bf16*  HW1T   = (bf16*) carve((size_t)HIDN * HIDN * 2);
    bf16*  HW2T   = (bf16*) carve((size_t)8 * HIDN * 2);
    bf16*  c_ln1s = (bf16*) carve((size_t)2 * HIDN * 2);
    bf16*  c_ln1b = (bf16*) carve((size_t)2 * HIDN * 2);
    bf16*  c_ln2s = (bf16*) carve((size_t)2 * HIDN * 2);
    bf16*  c_ln2b = (bf16*) carve((size_t)2 * HIDN * 2);
    bf16*  c_fb1  = (bf16*) carve((size_t)2 * FFN * 2);
    bf16*  c_fb2  = (bf16*) carve((size_t)2 * HIDN * 2);
    bf16*  c_hb1  = (bf16*) carve((size_t)HIDN * 2);
    bf16*  c_hb2  = (bf16*) carve((size_t)16 * 2);
    const size_t off_mand = off;
    bf16*  eattr_s = (bf16*) carve((size_t)(NE + 128) * EDIM * 2);
    const bool eg = (off <= ws_size);
    if (off_mand > ws_size) return;

    // CSR build scratch inside echunk (dead until layer loop):
    int* cnt    = (int*)echunk;
    int* cursor = cnt + NN;
    int* bsum   = cursor + NN;
    // Phase aliases: qk dead during agg phase -> bf16 agg overlays qk_b;
    // qk dead in FFN -> hid; v dead after agg -> tmp/ffnout.
    bf16*  agg_b  = qk_b;
    bf16*  tmp_b  = v_b;
    bf16*  hid    = qk_b;
    bf16*  ffnout = v_b;

    const int TB = 256;
    #define GRID1(n) dim3(((n) + TB - 1) / TB)

    convert4_kernel<<<GRID1(NN * HIDN / 4), TB, 0, stream>>>(xin, x_b, NN * HIDN / 4);
    convert_kernel<<<GRID1(2 * HIDN), TB, 0, stream>>>(ln1s, c_ln1s, 2 * HIDN);
    convert_kernel<<<GRID1(2 * HIDN), TB, 0, stream>>>(ln1b, c_ln1b, 2 * HIDN);
    convert_kernel<<<GRID1(2 * HIDN), TB, 0, stream>>>(ln2s, c_ln2s, 2 * HIDN);
    convert_kernel<<<GRID1(2 * HIDN), TB, 0, stream>>>(ln2b, c_ln2b, 2 * HIDN);
    convert_kernel<<<GRID1(2 * FFN), TB, 0, stream>>>(fb1, c_fb1, 2 * FFN);
    convert_kernel<<<GRID1(2 * HIDN), TB, 0, stream>>>(fb2, c_fb2, 2 * HIDN);
    convert_kernel<<<GRID1(HIDN), TB, 0, stream>>>(hb1, c_hb1, HIDN);
    convert_kernel<<<1, TB, 0, stream>>>(hb2, c_hb2, 7);
    transpose_kernel<<<GRID1(HIDN * HIDN / 4), TB, 0, stream>>>(hw1, HW1T, HIDN, HIDN);
    transpose_kernel<<<GRID1(HIDN * 7 / 4), TB, 0, stream>>>(hw2, HW2T, HIDN, 7);

    // ---- CSR build (once) ----
    hipMemsetAsync(cnt, 0, (size_t)NN * 4, stream);
    hist_kernel<<<GRID1(NE), TB, 0, stream>>>(dstI, cnt);
    scan1_kernel<<<NN / 256, 256, 0, stream>>>(cnt, rowp, bsum);
    scan2_kernel<<<1, 256, 0, stream>>>(bsum);
    scan3_kernel<<<NN / 256, 256, 0, stream>>>(rowp, bsum, cursor);
    scatter_kernel<<<GRID1(NE), TB, 0, stream>>>(srcI, dstI, cursor, perm, src_s, dst_s);
    if (eg) gather_kernel<<<GRID1(NE * 16), TB, 0, stream>>>(eattr, perm, eattr_s);

    for (int l = 0; l < 2; ++l) {
        const int dmin = l ? ASTART : 0;   // layer-2: dsts < ASTART never read
        const int rs   = l ? ASTART : 0;   // out-proj/FFN row range start
        const int rch  = (NN - rs) / 2;    // 32768 or 28672 (both %128==0)

        transpose_kernel<<<GRID1(HIDN * HIDN / 4), TB, 0, stream>>>(Wq + (size_t)l*HIDN*HIDN, WqkT, HIDN, HIDN);
        transpose_kernel<<<GRID1(HIDN * HIDN / 4), TB, 0, stream>>>(Wk + (size_t)l*HIDN*HIDN, WqkT + (size_t)HIDN*HIDN, HIDN, HIDN);
        transpose_kernel<<<GRID1(HIDN * HIDN / 4), TB, 0, stream>>>(Wv + (size_t)l*HIDN*HIDN, WvT, HIDN, HIDN);
        transpose_kernel<<<GRID1(EDIM * HIDN / 4), TB, 0, stream>>>(WeK + (size_t)l*EDIM*HIDN, WeKT, EDIM, HIDN);
        transpose_kernel<<<GRID1(EDIM * HIDN / 4), TB, 0, stream>>>(WeV + (size_t)l*EDIM*HIDN, WeVT, EDIM, HIDN);
        transpose_kernel<<<GRID1(HIDN * HIDN / 4), TB, 0, stream>>>(Wo + (size_t)l*HIDN*HIDN, WoT, HIDN, HIDN);
        transpose_kernel<<<GRID1(HIDN * FFN / 4),  TB, 0, stream>>>(fw1 + (size_t)l*HIDN*FFN, W1T, HIDN, FFN);
        transpose_kernel<<<GRID1(FFN * HIDN / 4),  TB, 0, stream>>>(fw2 + (size_t)l*FFN*HIDN, W2T, FFN, HIDN);

        // fused q|k projection (N=512) + separate v projection
        gemm_kernel<0, false><<<dim3((2*HIDN)/128, NN/128), TB, 0, stream>>>(x_b, WqkT, nullptr, qk_b, NN, 2*HIDN, HIDN, nullptr, 0);
        gemm_kernel<0, false><<<dim3(HIDN/128, NN/128), TB, 0, stream>>>(x_b, WvT, nullptr, v_b, NN, HIDN, HIDN, nullptr, 0);

        // score phase
        for (int c = 0; c < NCHUNK; ++c) {
            if (eg)
                gemm_kernel<0, false><<<dim3(HIDN/128, NCH/128), TB, 0, stream>>>(
                    eattr_s + (size_t)c * NCH * EDIM, WeKT, nullptr, echunk, NCH, HIDN, EDIM, nullptr, 0);
            else
                gemm_kernel<2, false><<<dim3(HIDN/128, NCH/128), TB, 0, stream>>>(
                    eattr, WeKT, nullptr, echunk, NCH, HIDN, EDIM, perm + (size_t)c * NCH, NE - c * NCH);
            score_kernel<<<NCH / 4, TB, 0, stream>>>(qk_b, qk_b + HIDN, echunk, src_s, dst_s, pbuf, c * NCH, 2 * HIDN, dmin);
        }

        // agg phase (bf16 agg overlays dead qk)
        for (int c = 0; c < NCHUNK; ++c) {
            if (eg)
                gemm_kernel<0, false><<<dim3(HIDN/128, NCHP/128), TB, 0, stream>>>(
                    eattr_s + (size_t)c * NCH * EDIM, WeVT, nullptr, echunk, NCHP, HIDN, EDIM, nullptr, 0);
            else
                gemm_kernel<2, false><<<dim3(HIDN/128, NCHP/128), TB, 0, stream>>>(
                    eattr, WeVT, nullptr, echunk, NCHP, HIDN, EDIM, perm + (size_t)c * NCH, NE - c * NCH);
            const int dlo = (c == 0) ? 0 : (c - 1) * DPC;
            const int dhi = (c == NCHUNK - 1) ? NN : (c + 2) * DPC;
            const int e1x = (c == NCHUNK - 1) ? NE + 1 : (c + 1) * NCH;
            agg_kernel<<<(dhi - dlo) / 4, TB, 0, stream>>>(
                pbuf, v_b, echunk, src_s, rowp, agg_b, c * NCH, e1x, dlo, dmin);
        }

        // out-proj (bf16 agg, AMODE0) rows >= rs, then LN1 in place
        gemm_kernel<0, false><<<dim3(HIDN/128, (NN - rs)/128), TB, 0, stream>>>(
            agg_b + (size_t)rs * HIDN, WoT, nullptr, tmp_b, NN - rs, HIDN, HIDN, nullptr, 0);
        ln_kernel<<<(NN - rs) / 4, TB, 0, stream>>>(
            x_b, tmp_b, c_ln1s + (size_t)l * HIDN, c_ln1b + (size_t)l * HIDN, rs);

        // FFN on rows >= rs (chunked so hid fits 64MB)
        for (int r0 = rs; r0 < NN; r0 += rch) {
            gemm_kernel<0, true ><<<dim3(FFN/128, rch/128), TB, 0, stream>>>(
                x_b + (size_t)r0 * HIDN, W1T, c_fb1 + (size_t)l * FFN, hid, rch, FFN, HIDN, nullptr, 0);
            gemm_kernel<0, false><<<dim3(HIDN/128, rch/128), TB, 0, stream>>>(
                hid, W2T, c_fb2 + (size_t)l * HIDN, ffnout, rch, HIDN, FFN, nullptr, 0);
            ln_kernel<<<rch / 4, TB, 0, stream>>>(
                x_b, ffnout, c_ln2s + (size_t)l * HIDN, c_ln2b + (size_t)l * HIDN, r0);
        }
    }

    gemm_kernel<0, true><<<dim3(HIDN/128, NACT/128), TB, 0, stream>>>(
        x_b + (size_t)ASTART * HIDN, HW1T, c_hb1, hid, NACT, HIDN, HIDN, nullptr, 0);
    head2_kernel<<<NACT / 4, TB, 0, stream>>>(hid, HW2T, c_hb2, (float*)d_out);
}